// Round 1
// baseline (74.495 us; speedup 1.0000x reference)
//
#include <hip/hip_runtime.h>

constexpr int PL = 128;
constexpr int NH = 4;

__global__ __launch_bounds__(256, 2) void fused_block_kernel(
    const float* __restrict__ x, const float* __restrict__ t, const int* __restrict__ mask,
    const float* __restrict__ Wq, const float* __restrict__ Wk, const float* __restrict__ Wv,
    const float* __restrict__ Wout, const float* __restrict__ W1, const float* __restrict__ b1,
    const float* __restrict__ W2, const float* __restrict__ b2,
    float* __restrict__ out)
{
    __shared__ float4 Q[NH][PL];
    __shared__ float4 K[NH][PL];
    __shared__ float4 V[NH][PL];
    __shared__ float4 O[PL][5];   // 5th float4 = pad for bank-conflict-free strided access
    __shared__ float validS[PL];
    __shared__ float w1s[64][16];
    __shared__ float cg[64];
    __shared__ float b1s[64];
    __shared__ float woutS[16];
    __shared__ float P[2][PL];
    __shared__ float bbS;

    const int tid = threadIdx.x;
    const int b = blockIdx.x;

    // ---- Phase 1: per-position Q/K/V build (rank-1 outer product + RoPE) ----
    if (tid < PL) {
        const int j = tid;
        const float xv = x[b * PL + j];
        const float tv = t[b * PL + j];
        const int mv = mask[b * PL + j];
        validS[j] = mv ? 1.0f : 0.0f;
        const float theta1 = 0.031622776601683794f;  // 1000^-0.5
        const float s0 = sinf(tv),          c0 = cosf(tv);
        const float s1 = sinf(tv * theta1), c1 = cosf(tv * theta1);
        const float xq = xv * 0.5f;  // fold q / sqrt(QK) = q / 2
        #pragma unroll
        for (int h = 0; h < NH; ++h) {
            const float wq0 = Wq[4*h+0], wq1 = Wq[4*h+1], wq2 = Wq[4*h+2], wq3 = Wq[4*h+3];
            const float wk0 = Wk[4*h+0], wk1 = Wk[4*h+1], wk2 = Wk[4*h+2], wk3 = Wk[4*h+3];
            const float wv0 = Wv[4*h+0], wv1 = Wv[4*h+1], wv2 = Wv[4*h+2], wv3 = Wv[4*h+3];
            Q[h][j] = make_float4(xq*(wq0*c0 - wq1*s0), xq*(wq0*s0 + wq1*c0),
                                  xq*(wq2*c1 - wq3*s1), xq*(wq2*s1 + wq3*c1));
            K[h][j] = make_float4(xv*(wk0*c0 - wk1*s0), xv*(wk0*s0 + wk1*c0),
                                  xv*(wk2*c1 - wk3*s1), xv*(wk2*s1 + wk3*c1));
            V[h][j] = make_float4(xv*wv0, xv*wv1, xv*wv2, xv*wv3);
        }
    }
    // ---- weight staging (all threads) ----
    for (int idx = tid; idx < 1024; idx += 256) (&w1s[0][0])[idx] = W1[idx];
    if (tid < 64) {
        b1s[tid] = b1[tid];
        float c = 0.f;
        #pragma unroll
        for (int d = 0; d < 16; ++d) c += W2[d * 64 + tid] * Wout[d];  // W2^T @ wout
        cg[tid] = c;
    }
    if (tid < 16) woutS[tid] = Wout[tid];
    if (tid == 0) {
        float bb = 0.f;
        #pragma unroll
        for (int d = 0; d < 16; ++d) bb += b2[d] * Wout[d];
        bbS = bb;
    }
    __syncthreads();

    // ---- Phase 2: attention. 512 (h,qi) rows over 256 threads, 2 each. ----
    // Wave lanes share h -> K[h][j]/V[h][j] reads are wave-uniform broadcasts.
    #pragma unroll
    for (int it = 0; it < 2; ++it) {
        const int item = tid + it * 256;
        const int h = item >> 7;
        const int qi = item & (PL - 1);
        const float4 q = Q[h][qi];
        const bool mq = (validS[qi] != 0.0f);
        float s = 0.f, ax = 0.f, ay = 0.f, az = 0.f, aw = 0.f;
        #pragma unroll 4
        for (int j = 0; j < PL; ++j) {
            const float4 k = K[h][j];
            const float4 v = V[h][j];
            const float l = q.x*k.x + q.y*k.y + q.z*k.z + q.w*k.w;
            // valid row: softmax weight = valid_j * exp(l)  (no max-sub needed: |l| < 4)
            // masked row (m_qi=0): reference gives uniform 1/128 over ALL j -> w = 1
            const float p = validS[j] * __expf(l);
            const float w = mq ? p : 1.0f;
            s  += w;
            ax += w * v.x; ay += w * v.y; az += w * v.z; aw += w * v.w;
        }
        const float inv = 1.0f / s;
        O[qi][h] = make_float4(ax * inv, ay * inv, az * inv, aw * inv);
    }
    __syncthreads();

    // ---- Phase 3: FFN + residual + out-proj, folded:
    //   out = o.wout + b2.wout + sum_hid cg[hid]*relu(o.W1[hid] + b1[hid])
    // split 64 hids across two half-blocks, combine via LDS.
    {
        const int qi = tid & (PL - 1);
        const int half = tid >> 7;
        float o[16];
        #pragma unroll
        for (int g = 0; g < 4; ++g) {
            const float4 v = O[qi][g];
            o[4*g+0] = v.x; o[4*g+1] = v.y; o[4*g+2] = v.z; o[4*g+3] = v.w;
        }
        float r = 0.f;
        const int h0 = half * 32;
        #pragma unroll 4
        for (int hid2 = 0; hid2 < 32; ++hid2) {
            const int hid = h0 + hid2;
            float hsum = b1s[hid];
            #pragma unroll
            for (int d = 0; d < 16; ++d) hsum += o[d] * w1s[hid][d];
            r += cg[hid] * fmaxf(hsum, 0.f);
        }
        if (half == 0) {
            float r2 = bbS;
            #pragma unroll
            for (int d = 0; d < 16; ++d) r2 += o[d] * woutS[d];
            r += r2;
        }
        P[half][qi] = r;
    }
    __syncthreads();
    if (tid < PL) out[b * PL + tid] = P[0][tid] + P[1][tid];
}

extern "C" void kernel_launch(void* const* d_in, const int* in_sizes, int n_in,
                              void* d_out, int out_size, void* d_ws, size_t ws_size,
                              hipStream_t stream) {
    const float* x    = (const float*)d_in[0];
    const float* t    = (const float*)d_in[1];
    const int*   mask = (const int*)d_in[2];
    const float* Wq   = (const float*)d_in[3];
    const float* Wk   = (const float*)d_in[4];
    const float* Wv   = (const float*)d_in[5];
    const float* Wout = (const float*)d_in[6];
    const float* W1   = (const float*)d_in[7];
    const float* b1   = (const float*)d_in[8];
    const float* W2   = (const float*)d_in[9];
    const float* b2   = (const float*)d_in[10];
    float* outp = (float*)d_out;
    const int B = in_sizes[0] / PL;  // 2048 sequences
    fused_block_kernel<<<B, 256, 0, stream>>>(x, t, mask, Wq, Wk, Wv, Wout, W1, b1, W2, b2, outp);
}

// Round 2
// 50.808 us; speedup vs baseline: 1.4662x; 1.4662x over previous
//
#include <hip/hip_runtime.h>

constexpr int PL = 128;
constexpr int NH = 4;

__device__ __forceinline__ float fast_exp2(float x) {
#if __has_builtin(__builtin_amdgcn_exp2f)
    return __builtin_amdgcn_exp2f(x);
#else
    return __expf(x * 0.69314718055994531f);   // e^(x ln2) = 2^x
#endif
}

__global__ __launch_bounds__(256, 4) void fused_block_kernel(
    const float* __restrict__ x, const float* __restrict__ t, const int* __restrict__ mask,
    const float* __restrict__ Wq, const float* __restrict__ Wk, const float* __restrict__ Wv,
    const float* __restrict__ Wout, const float* __restrict__ W1, const float* __restrict__ b1,
    const float* __restrict__ W2, const float* __restrict__ b2,
    float* __restrict__ out)
{
    __shared__ float4 Qs[NH][PL];        // pre-scaled by 0.5*log2(e)*x
    __shared__ float4 Ks[NH][PL];
    __shared__ float4 O[PL][5];          // pad -> conflict-free strided access
    __shared__ float2 mj[PL];            // (valid_j, valid_j * x_j)
    __shared__ float  w1s[64][16];
    __shared__ float  cg[64];
    __shared__ float  b1s[64];
    __shared__ float  woutS[16];
    __shared__ float  P[2][PL];
    __shared__ float  xpart[2];
    __shared__ float  bbS;

    const int tid = threadIdx.x;
    const int b   = blockIdx.x;
    const int j   = tid & (PL - 1);
    const int hh  = tid >> 7;            // 0 -> heads {0,1}, 1 -> heads {2,3}

    // ---- Phase 1: rank-1 Q/K build + RoPE (V is NOT materialized: v_j = x_j*wv) ----
    const float xv = x[b * PL + j];
    const float tv = t[b * PL + j];
    const int   mv = mask[b * PL + j];
    const float va = mv ? 1.0f : 0.0f;

    if (hh == 0) {
        mj[j] = make_float2(va, va * xv);
        float px = xv;                   // block-wide sum(x) via 2 wave reduces
        #pragma unroll
        for (int off = 32; off >= 1; off >>= 1) px += __shfl_xor(px, off);
        if ((tid & 63) == 0) xpart[tid >> 6] = px;
    }

    {
        const float th1 = 0.031622776601683794f;   // 1000^-0.5
        const float s0 = __sinf(tv),        c0 = __cosf(tv);
        const float s1 = __sinf(tv * th1),  c1 = __cosf(tv * th1);
        const float qsc = xv * (0.5f * 1.4426950408889634f);  // fold 1/sqrt(QK) and log2(e)
        #pragma unroll
        for (int hi = 0; hi < 2; ++hi) {
            const int h = hh * 2 + hi;
            const float wq0=Wq[4*h+0], wq1=Wq[4*h+1], wq2=Wq[4*h+2], wq3=Wq[4*h+3];
            const float wk0=Wk[4*h+0], wk1=Wk[4*h+1], wk2=Wk[4*h+2], wk3=Wk[4*h+3];
            Qs[h][j] = make_float4(qsc*(wq0*c0 - wq1*s0), qsc*(wq0*s0 + wq1*c0),
                                   qsc*(wq2*c1 - wq3*s1), qsc*(wq2*s1 + wq3*c1));
            Ks[h][j] = make_float4(xv*(wk0*c0 - wk1*s0), xv*(wk0*s0 + wk1*c0),
                                   xv*(wk2*c1 - wk3*s1), xv*(wk2*s1 + wk3*c1));
        }
    }

    // ---- weight staging ----
    for (int idx = tid; idx < 1024; idx += 256) (&w1s[0][0])[idx] = W1[idx];
    if (tid < 64) {
        b1s[tid] = b1[tid];
        float c = 0.f;
        #pragma unroll
        for (int d = 0; d < 16; ++d) c += W2[d * 64 + tid] * Wout[d];   // W2^T @ wout
        cg[tid] = c;
    }
    if (tid < 16) woutS[tid] = Wout[tid];
    if (tid == 0) {
        float bb = 0.f;
        #pragma unroll
        for (int d = 0; d < 16; ++d) bb += b2[d] * Wout[d];
        bbS = bb;
    }
    __syncthreads();

    // ---- Phase 2: attention. h = tid>>6 (wave-uniform); 2 query rows/thread share K reads.
    {
        const int h    = tid >> 6;
        const int qa_i = tid & 63;
        const int qb_i = qa_i + 64;
        const float4 qa = Qs[h][qa_i];
        const float4 qb = Qs[h][qb_i];
        float sA = 0.f, wxA = 0.f, sB = 0.f, wxB = 0.f;
        #pragma unroll 8
        for (int jj = 0; jj < PL; ++jj) {
            const float4 k = Ks[h][jj];      // broadcast b128
            const float2 m = mj[jj];         // broadcast b64
            const float lA = qa.x*k.x + qa.y*k.y + qa.z*k.z + qa.w*k.w;
            const float lB = qb.x*k.x + qb.y*k.y + qb.z*k.z + qb.w*k.w;
            const float eA = fast_exp2(lA);  // = exp(orig logit), valid-j masking via m
            const float eB = fast_exp2(lB);
            sA  = fmaf(m.x, eA, sA);  wxA = fmaf(m.y, eA, wxA);
            sB  = fmaf(m.x, eB, sB);  wxB = fmaf(m.y, eB, wxB);
        }
        // masked query row: softmax over ALL j uniform -> o = wv * sum(x)/128
        const float sumx = xpart[0] + xpart[1];
        const float4 wv  = reinterpret_cast<const float4*>(Wv)[h];
        const bool  mA   = mj[qa_i].x != 0.f;
        const bool  mB   = mj[qb_i].x != 0.f;
        const float oA   = (mA ? wxA : sumx) / (mA ? sA : 128.f);
        const float oB   = (mB ? wxB : sumx) / (mB ? sB : 128.f);
        O[qa_i][h] = make_float4(wv.x*oA, wv.y*oA, wv.z*oA, wv.w*oA);
        O[qb_i][h] = make_float4(wv.x*oB, wv.y*oB, wv.z*oB, wv.w*oB);
    }
    __syncthreads();

    // ---- Phase 3: out = o.wout + b2.wout + sum_hid cg[hid]*relu(o.W1[hid]+b1[hid]) ----
    {
        const int qi   = tid & (PL - 1);
        const int half = tid >> 7;
        const float4 o0 = O[qi][0], o1 = O[qi][1], o2 = O[qi][2], o3 = O[qi][3];
        float r = 0.f;
        const int h0 = half * 32;
        #pragma unroll 8
        for (int hid2 = 0; hid2 < 32; ++hid2) {
            const int hid = h0 + hid2;
            const float4* wr = reinterpret_cast<const float4*>(&w1s[hid][0]);
            const float4 a0 = wr[0], a1 = wr[1], a2 = wr[2], a3 = wr[3];
            float hsum = b1s[hid]
                + o0.x*a0.x + o0.y*a0.y + o0.z*a0.z + o0.w*a0.w
                + o1.x*a1.x + o1.y*a1.y + o1.z*a1.z + o1.w*a1.w
                + o2.x*a2.x + o2.y*a2.y + o2.z*a2.z + o2.w*a2.w
                + o3.x*a3.x + o3.y*a3.y + o3.z*a3.z + o3.w*a3.w;
            r += cg[hid] * fmaxf(hsum, 0.f);
        }
        if (half == 0) {
            const float4* wo = reinterpret_cast<const float4*>(&woutS[0]);
            const float4 b0 = wo[0], b1v = wo[1], b2v = wo[2], b3 = wo[3];
            float r2 = bbS
                + o0.x*b0.x  + o0.y*b0.y  + o0.z*b0.z  + o0.w*b0.w
                + o1.x*b1v.x + o1.y*b1v.y + o1.z*b1v.z + o1.w*b1v.w
                + o2.x*b2v.x + o2.y*b2v.y + o2.z*b2v.z + o2.w*b2v.w
                + o3.x*b3.x  + o3.y*b3.y  + o3.z*b3.z  + o3.w*b3.w;
            r += r2;
        }
        P[half][qi] = r;
    }
    __syncthreads();
    if (tid < PL) out[b * PL + tid] = P[0][tid] + P[1][tid];
}

extern "C" void kernel_launch(void* const* d_in, const int* in_sizes, int n_in,
                              void* d_out, int out_size, void* d_ws, size_t ws_size,
                              hipStream_t stream) {
    const float* x    = (const float*)d_in[0];
    const float* t    = (const float*)d_in[1];
    const int*   mask = (const int*)d_in[2];
    const float* Wq   = (const float*)d_in[3];
    const float* Wk   = (const float*)d_in[4];
    const float* Wv   = (const float*)d_in[5];
    const float* Wout = (const float*)d_in[6];
    const float* W1   = (const float*)d_in[7];
    const float* b1   = (const float*)d_in[8];
    const float* W2   = (const float*)d_in[9];
    const float* b2   = (const float*)d_in[10];
    float* outp = (float*)d_out;
    const int B = in_sizes[0] / PL;  // 2048 sequences
    fused_block_kernel<<<B, 256, 0, stream>>>(x, t, mask, Wq, Wk, Wv, Wout, W1, b1, W2, b2, outp);
}

// Round 5
// 45.532 us; speedup vs baseline: 1.6361x; 1.1159x over previous
//
#include <hip/hip_runtime.h>

constexpr int PL = 128;
constexpr int NH = 4;

typedef float f32x2 __attribute__((ext_vector_type(2)));

__device__ __forceinline__ float fast_exp2(float x) {
#if __has_builtin(__builtin_amdgcn_exp2f)
    return __builtin_amdgcn_exp2f(x);
#else
    return __expf(x * 0.69314718055994531f);
#endif
}

// Packed f32 pair math via C vector semantics (exact IEEE f32 FMA per lane).
// Backend may select v_pk_fma_f32 / v_pk_mul_f32 (gfx90a+ packed-f32) — either
// way the result is bit-identical to two scalar fmaf's.
__device__ __forceinline__ f32x2 pk_fma(f32x2 a, f32x2 b, f32x2 c) {
    return __builtin_elementwise_fma(a, b, c);
}

__global__ __launch_bounds__(256, 4) void fused_block_kernel(
    const float* __restrict__ x, const float* __restrict__ t, const int* __restrict__ mask,
    const float* __restrict__ Wq, const float* __restrict__ Wk, const float* __restrict__ Wv,
    const float* __restrict__ Wout, const float* __restrict__ W1, const float* __restrict__ b1,
    const float* __restrict__ W2, const float* __restrict__ b2,
    float* __restrict__ out)
{
    __shared__ float4 Qs[NH][PL];        // pre-scaled by 0.5*log2(e)*x
    __shared__ float4 KA[NH][64];        // {kx(2j),kx(2j+1),ky(2j),ky(2j+1)}
    __shared__ float4 KB[NH][64];        // {kz,kz',kw,kw'}
    __shared__ float4 MV[64];            // {v,v',v*x,(v*x)'}
    __shared__ float4 O[PL][5];          // pad -> conflict-free strided access
    __shared__ float  w1s[64][16];
    __shared__ float  cg[64];
    __shared__ float  b1s[64];
    __shared__ float  woutS[16];
    __shared__ float  P[2][PL];
    __shared__ float  xpart[2];
    __shared__ float  bbS;

    const int tid = threadIdx.x;
    const int b   = blockIdx.x;
    const int j   = tid & (PL - 1);
    const int hh  = tid >> 7;
    const int j2  = j >> 1;
    const int par = j & 1;

    // ---- Phase 1: rank-1 Q/K build + RoPE; K staged in pair-SoA for packed phase 2 ----
    const float xv = x[b * PL + j];
    const float tv = t[b * PL + j];
    const int   mv = mask[b * PL + j];
    const float va = mv ? 1.0f : 0.0f;

    if (hh == 0) {
        float* MVf = reinterpret_cast<float*>(MV);
        MVf[(j2 << 2) + par]     = va;
        MVf[(j2 << 2) + 2 + par] = va * xv;
        float px = xv;
        #pragma unroll
        for (int off = 32; off >= 1; off >>= 1) px += __shfl_xor(px, off);
        if ((tid & 63) == 0) xpart[tid >> 6] = px;
    }

    {
        const float th1 = 0.031622776601683794f;   // 1000^-0.5
        const float s0 = __sinf(tv),        c0 = __cosf(tv);
        const float s1 = __sinf(tv * th1),  c1 = __cosf(tv * th1);
        const float qsc = xv * (0.5f * 1.4426950408889634f);  // fold 1/sqrt(QK), log2(e)
        float* KAf = reinterpret_cast<float*>(KA);
        float* KBf = reinterpret_cast<float*>(KB);
        #pragma unroll
        for (int hi = 0; hi < 2; ++hi) {
            const int h = hh * 2 + hi;
            const float wq0=Wq[4*h+0], wq1=Wq[4*h+1], wq2=Wq[4*h+2], wq3=Wq[4*h+3];
            const float wk0=Wk[4*h+0], wk1=Wk[4*h+1], wk2=Wk[4*h+2], wk3=Wk[4*h+3];
            Qs[h][j] = make_float4(qsc*(wq0*c0 - wq1*s0), qsc*(wq0*s0 + wq1*c0),
                                   qsc*(wq2*c1 - wq3*s1), qsc*(wq2*s1 + wq3*c1));
            const int base = ((h * 64 + j2) << 2);
            KAf[base + par]     = xv*(wk0*c0 - wk1*s0);
            KAf[base + 2 + par] = xv*(wk0*s0 + wk1*c0);
            KBf[base + par]     = xv*(wk2*c1 - wk3*s1);
            KBf[base + 2 + par] = xv*(wk2*s1 + wk3*c1);
        }
    }

    // ---- weight staging ----
    for (int idx = tid; idx < 1024; idx += 256) (&w1s[0][0])[idx] = W1[idx];
    if (tid < 64) {
        b1s[tid] = b1[tid];
        float c = 0.f;
        #pragma unroll
        for (int d = 0; d < 16; ++d) c += W2[d * 64 + tid] * Wout[d];   // W2^T @ wout
        cg[tid] = c;
    }
    if (tid < 16) woutS[tid] = Wout[tid];
    if (tid == 0) {
        float bb = 0.f;
        #pragma unroll
        for (int d = 0; d < 16; ++d) bb += b2[d] * Wout[d];
        bbS = bb;
    }
    __syncthreads();

    // ---- Phase 2: attention; packed over adjacent j pairs, 2 query rows/thread ----
    {
        const int h    = tid >> 6;              // wave-uniform head
        const int qa_i = tid & 63;
        const int qb_i = qa_i + 64;
        const float4 qA = Qs[h][qa_i];
        const float4 qB = Qs[h][qb_i];
        const f32x2 qax = {qA.x, qA.x}, qay = {qA.y, qA.y}, qaz = {qA.z, qA.z}, qaw = {qA.w, qA.w};
        const f32x2 qbx = {qB.x, qB.x}, qby = {qB.y, qB.y}, qbz = {qB.z, qB.z}, qbw = {qB.w, qB.w};
        f32x2 sA = {0.f, 0.f}, xA = {0.f, 0.f};
        f32x2 sB = {0.f, 0.f}, xB = {0.f, 0.f};
        #pragma unroll 8
        for (int jj = 0; jj < 64; ++jj) {
            const float4 ka = KA[h][jj];        // broadcast b128
            const float4 kb = KB[h][jj];
            const float4 mm = MV[jj];
            const f32x2 kx = {ka.x, ka.y}, ky = {ka.z, ka.w};
            const f32x2 kz = {kb.x, kb.y}, kw = {kb.z, kb.w};
            const f32x2 vv = {mm.x, mm.y}, vx = {mm.z, mm.w};
            f32x2 LA = qax * kx;                // v2f32 mul (exact per-lane)
            LA = pk_fma(qay, ky, LA);
            LA = pk_fma(qaz, kz, LA);
            LA = pk_fma(qaw, kw, LA);
            f32x2 LB = qbx * kx;
            LB = pk_fma(qby, ky, LB);
            LB = pk_fma(qbz, kz, LB);
            LB = pk_fma(qbw, kw, LB);
            f32x2 EA, EB;
            EA.x = fast_exp2(LA.x); EA.y = fast_exp2(LA.y);
            EB.x = fast_exp2(LB.x); EB.y = fast_exp2(LB.y);
            sA = pk_fma(EA, vv, sA);  xA = pk_fma(EA, vx, xA);
            sB = pk_fma(EB, vv, sB);  xB = pk_fma(EB, vx, xB);
        }
        const float sAs = sA.x + sA.y, wxA = xA.x + xA.y;
        const float sBs = sB.x + sB.y, wxB = xB.x + xB.y;
        const float sumx = xpart[0] + xpart[1];
        const float4 wv  = reinterpret_cast<const float4*>(Wv)[h];
        const float* MVf = reinterpret_cast<const float*>(MV);
        const bool mA = MVf[((qa_i >> 1) << 2) + (qa_i & 1)] != 0.f;
        const bool mB = MVf[((qb_i >> 1) << 2) + (qb_i & 1)] != 0.f;
        const float oA = (mA ? wxA : sumx) / (mA ? sAs : 128.f);
        const float oB = (mB ? wxB : sumx) / (mB ? sBs : 128.f);
        O[qa_i][h] = make_float4(wv.x*oA, wv.y*oA, wv.z*oA, wv.w*oA);
        O[qb_i][h] = make_float4(wv.x*oB, wv.y*oB, wv.z*oB, wv.w*oB);
    }
    __syncthreads();

    // ---- Phase 3: out = o.wout + b2.wout + sum_hid cg[hid]*relu(o.W1[hid]+b1[hid]) ----
    {
        const int qi   = tid & (PL - 1);
        const int half = tid >> 7;
        const float4 o0 = O[qi][0], o1 = O[qi][1], o2 = O[qi][2], o3 = O[qi][3];
        float r = 0.f;
        const int h0 = half * 32;
        #pragma unroll 8
        for (int hid2 = 0; hid2 < 32; ++hid2) {
            const int hid = h0 + hid2;
            const float4* wr = reinterpret_cast<const float4*>(&w1s[hid][0]);
            const float4 a0 = wr[0], a1 = wr[1], a2 = wr[2], a3 = wr[3];
            float hsum = b1s[hid]
                + o0.x*a0.x + o0.y*a0.y + o0.z*a0.z + o0.w*a0.w
                + o1.x*a1.x + o1.y*a1.y + o1.z*a1.z + o1.w*a1.w
                + o2.x*a2.x + o2.y*a2.y + o2.z*a2.z + o2.w*a2.w
                + o3.x*a3.x + o3.y*a3.y + o3.z*a3.z + o3.w*a3.w;
            r += cg[hid] * fmaxf(hsum, 0.f);
        }
        if (half == 0) {
            const float4* wo = reinterpret_cast<const float4*>(&woutS[0]);
            const float4 w0 = wo[0], w1v = wo[1], w2v = wo[2], w3 = wo[3];
            float r2 = bbS
                + o0.x*w0.x  + o0.y*w0.y  + o0.z*w0.z  + o0.w*w0.w
                + o1.x*w1v.x + o1.y*w1v.y + o1.z*w1v.z + o1.w*w1v.w
                + o2.x*w2v.x + o2.y*w2v.y + o2.z*w2v.z + o2.w*w2v.w
                + o3.x*w3.x  + o3.y*w3.y  + o3.z*w3.z  + o3.w*w3.w;
            r += r2;
        }
        P[half][qi] = r;
    }
    __syncthreads();
    if (tid < PL) out[b * PL + tid] = P[0][tid] + P[1][tid];
}

extern "C" void kernel_launch(void* const* d_in, const int* in_sizes, int n_in,
                              void* d_out, int out_size, void* d_ws, size_t ws_size,
                              hipStream_t stream) {
    const float* x    = (const float*)d_in[0];
    const float* t    = (const float*)d_in[1];
    const int*   mask = (const int*)d_in[2];
    const float* Wq   = (const float*)d_in[3];
    const float* Wk   = (const float*)d_in[4];
    const float* Wv   = (const float*)d_in[5];
    const float* Wout = (const float*)d_in[6];
    const float* W1   = (const float*)d_in[7];
    const float* b1   = (const float*)d_in[8];
    const float* W2   = (const float*)d_in[9];
    const float* b2   = (const float*)d_in[10];
    float* outp = (float*)d_out;
    const int B = in_sizes[0] / PL;  // 2048 sequences
    fused_block_kernel<<<B, 256, 0, stream>>>(x, t, mask, Wq, Wk, Wv, Wout, W1, b1, W2, b2, outp);
}

// Round 6
// 35.816 us; speedup vs baseline: 2.0799x; 1.2713x over previous
//
#include <hip/hip_runtime.h>

constexpr int PL = 128;

typedef float f32x2 __attribute__((ext_vector_type(2)));

__device__ __forceinline__ float fast_exp2(float x) {
#if __has_builtin(__builtin_amdgcn_exp2f)
    return __builtin_amdgcn_exp2f(x);
#else
    return __expf(x * 0.69314718055994531f);   // e^(x ln2) = 2^x
#endif
}
// exact IEEE f32 fma per lane; backend free to select v_pk_fma_f32 (proven in round 5)
__device__ __forceinline__ f32x2 pk_fma(f32x2 a, f32x2 b, f32x2 c) {
    return __builtin_elementwise_fma(a, b, c);
}
__device__ __forceinline__ f32x2 sp(float v) { f32x2 r; r.x = v; r.y = v; return r; }

__global__ __launch_bounds__(128, 4) void fused_block_kernel(
    const float* __restrict__ x, const float* __restrict__ t, const int* __restrict__ mask,
    const float* __restrict__ Wq, const float* __restrict__ Wk, const float* __restrict__ Wv,
    const float* __restrict__ Wout, const float* __restrict__ W1, const float* __restrict__ b1,
    const float* __restrict__ W2, const float* __restrict__ b2,
    float* __restrict__ out)
{
    // per-j shared data, head-independent, j-pair SoA:
    // CSM[jp*3+0] = {x*c0 (2j), x*c0 (2j+1), x*s0, x*s0'}
    // CSM[jp*3+1] = {x*c1, x*c1', x*s1, x*s1'}
    // CSM[jp*3+2] = {valid, valid', valid*x, (valid*x)'}
    __shared__ float4 CSM[64 * 3];
    __shared__ f32x2  w1p[32][16];     // [hid-pair][dim] = {W1[2p][d], W1[2p+1][d]}
    __shared__ __align__(8) float cg[64];
    __shared__ __align__(8) float b1s[64];
    __shared__ float4 OS4[PL];          // per-row per-head attention scalar o_scal
    __shared__ float  xpart[2];
    __shared__ float  bbS;

    const int tid = threadIdx.x;
    const int b   = blockIdx.x;

    // ---- Phase 1: per-position trig staging (head-independent!) ----
    {
        const int j  = tid;
        const int jp = j >> 1, p = j & 1;
        const float xv = x[b * PL + j];
        const float tv = t[b * PL + j];
        const int   mv = mask[b * PL + j];
        const float va = mv ? 1.0f : 0.0f;
        const float th1 = 0.031622776601683794f;   // 1000^-0.5
        const float c0 = __cosf(tv),       s0 = __sinf(tv);
        const float c1 = __cosf(tv * th1), s1 = __sinf(tv * th1);
        float* CSMf = reinterpret_cast<float*>(CSM);
        CSMf[jp*12 + 0 + p] = xv * c0;
        CSMf[jp*12 + 2 + p] = xv * s0;
        CSMf[jp*12 + 4 + p] = xv * c1;
        CSMf[jp*12 + 6 + p] = xv * s1;
        CSMf[jp*12 + 8 + p] = va;
        CSMf[jp*12 +10 + p] = va * xv;
        float px = xv;
        #pragma unroll
        for (int off = 32; off >= 1; off >>= 1) px += __shfl_xor(px, off);
        if ((tid & 63) == 0) xpart[tid >> 6] = px;
    }
    // ---- weight staging ----
    for (int idx = tid; idx < 1024; idx += 128) {
        const int hid = idx >> 4, d = idx & 15;
        reinterpret_cast<float*>(w1p)[((hid >> 1) * 16 + d) * 2 + (hid & 1)] = W1[idx];
    }
    if (tid < 64) {
        b1s[tid] = b1[tid];
        float c = 0.f;
        #pragma unroll
        for (int d = 0; d < 16; ++d) c += W2[d * 64 + tid] * Wout[d];   // W2^T @ wout
        cg[tid] = c;
    }
    if (tid == 0) {
        float bb = 0.f;
        #pragma unroll
        for (int d = 0; d < 16; ++d) bb += b2[d] * Wout[d];
        bbS = bb;
    }
    __syncthreads();

    // ---- Phase 2: attention via relative-position form; 4 rows/thread, 1 head ----
    {
        const int h  = tid >> 5;            // 0..3, wave-uniform j-data regardless
        const int r0 = tid & 31;
        const float4 wq4 = reinterpret_cast<const float4*>(Wq)[h];
        const float4 wk4 = reinterpret_cast<const float4*>(Wk)[h];
        const float a0  = wq4.x*wk4.x + wq4.y*wk4.y;
        const float be0 = wq4.x*wk4.y - wq4.y*wk4.x;
        const float a1  = wq4.z*wk4.z + wq4.w*wk4.w;
        const float be1 = wq4.z*wk4.w - wq4.w*wk4.z;
        const float gam = 0.5f * 1.4426950408889634f;   // 1/sqrt(QK) * log2(e)

        float A[4], Bc[4], Cc[4], Dc[4], vr[4];
        const float* CSMf = reinterpret_cast<const float*>(CSM);
        #pragma unroll
        for (int rr = 0; rr < 4; ++rr) {
            const int r = r0 + rr * 32;
            const int base = (r >> 1) * 12 + (r & 1);
            const float xc0 = CSMf[base + 0], xs0 = CSMf[base + 2];
            const float xc1 = CSMf[base + 4], xs1 = CSMf[base + 6];
            vr[rr] = CSMf[base + 8];
            A[rr]  = gam * (xc0 * a0 + xs0 * be0);
            Bc[rr] = gam * (xs0 * a0 - xc0 * be0);
            Cc[rr] = gam * (xc1 * a1 + xs1 * be1);
            Dc[rr] = gam * (xs1 * a1 - xc1 * be1);
        }
        f32x2 S[4], X[4];
        #pragma unroll
        for (int rr = 0; rr < 4; ++rr) { S[rr] = sp(0.f); X[rr] = sp(0.f); }

        #pragma unroll 4
        for (int jj = 0; jj < 64; ++jj) {
            const float4 ca = CSM[jj * 3 + 0];   // broadcast b128
            const float4 cb = CSM[jj * 3 + 1];
            const float4 mm = CSM[jj * 3 + 2];
            f32x2 c0p; c0p.x = ca.x; c0p.y = ca.y;
            f32x2 s0p; s0p.x = ca.z; s0p.y = ca.w;
            f32x2 c1p; c1p.x = cb.x; c1p.y = cb.y;
            f32x2 s1p; s1p.x = cb.z; s1p.y = cb.w;
            f32x2 vv;  vv.x  = mm.x; vv.y  = mm.y;
            f32x2 vx;  vx.x  = mm.z; vx.y  = mm.w;
            #pragma unroll
            for (int rr = 0; rr < 4; ++rr) {
                f32x2 L = sp(A[rr]) * c0p;
                L = pk_fma(sp(Bc[rr]), s0p, L);
                L = pk_fma(sp(Cc[rr]), c1p, L);
                L = pk_fma(sp(Dc[rr]), s1p, L);
                f32x2 E;
                E.x = fast_exp2(L.x);
                E.y = fast_exp2(L.y);
                S[rr] = pk_fma(E, vv, S[rr]);
                X[rr] = pk_fma(E, vx, X[rr]);
            }
        }
        const float sumx = xpart[0] + xpart[1];
        float* OSf = reinterpret_cast<float*>(OS4);
        #pragma unroll
        for (int rr = 0; rr < 4; ++rr) {
            const int r = r0 + rr * 32;
            const float s  = S[rr].x + S[rr].y;
            const float wx = X[rr].x + X[rr].y;
            const bool  mr = vr[rr] != 0.f;
            // masked query row: uniform softmax over ALL j -> o_scal = sumx/128
            OSf[r * 4 + h] = (mr ? wx : sumx) / (mr ? s : 128.f);
        }
    }
    __syncthreads();

    // ---- Phase 3: o = wv (x) o_scal; out = o.wout + bb + sum cg*relu(o.W1+b1) ----
    {
        const int qi = tid;
        const float4 osc = OS4[qi];
        const float4 wv0 = reinterpret_cast<const float4*>(Wv)[0];
        const float4 wv1 = reinterpret_cast<const float4*>(Wv)[1];
        const float4 wv2 = reinterpret_cast<const float4*>(Wv)[2];
        const float4 wv3 = reinterpret_cast<const float4*>(Wv)[3];
        float o[16];
        o[ 0] = wv0.x*osc.x; o[ 1] = wv0.y*osc.x; o[ 2] = wv0.z*osc.x; o[ 3] = wv0.w*osc.x;
        o[ 4] = wv1.x*osc.y; o[ 5] = wv1.y*osc.y; o[ 6] = wv1.z*osc.y; o[ 7] = wv1.w*osc.y;
        o[ 8] = wv2.x*osc.z; o[ 9] = wv2.y*osc.z; o[10] = wv2.z*osc.z; o[11] = wv2.w*osc.z;
        o[12] = wv3.x*osc.w; o[13] = wv3.y*osc.w; o[14] = wv3.z*osc.w; o[15] = wv3.w*osc.w;

        const f32x2* b1pair = reinterpret_cast<const f32x2*>(b1s);
        const f32x2* cgpair = reinterpret_cast<const f32x2*>(cg);
        f32x2 R2 = sp(0.f);
        #pragma unroll 4
        for (int pp = 0; pp < 32; ++pp) {
            f32x2 HS = b1pair[pp];
            #pragma unroll
            for (int d = 0; d < 16; ++d) HS = pk_fma(w1p[pp][d], sp(o[d]), HS);
            HS.x = fmaxf(HS.x, 0.f);
            HS.y = fmaxf(HS.y, 0.f);
            R2 = pk_fma(cgpair[pp], HS, R2);
        }
        float r2 = bbS;
        #pragma unroll
        for (int d = 0; d < 16; ++d) r2 += o[d] * Wout[d];
        out[b * PL + qi] = R2.x + R2.y + r2;
    }
}

extern "C" void kernel_launch(void* const* d_in, const int* in_sizes, int n_in,
                              void* d_out, int out_size, void* d_ws, size_t ws_size,
                              hipStream_t stream) {
    const float* x    = (const float*)d_in[0];
    const float* t    = (const float*)d_in[1];
    const int*   mask = (const int*)d_in[2];
    const float* Wq   = (const float*)d_in[3];
    const float* Wk   = (const float*)d_in[4];
    const float* Wv   = (const float*)d_in[5];
    const float* Wout = (const float*)d_in[6];
    const float* W1   = (const float*)d_in[7];
    const float* b1   = (const float*)d_in[8];
    const float* W2   = (const float*)d_in[9];
    const float* b2   = (const float*)d_in[10];
    float* outp = (float*)d_out;
    const int B = in_sizes[0] / PL;  // 2048 sequences
    fused_block_kernel<<<B, 128, 0, stream>>>(x, t, mask, Wq, Wk, Wv, Wout, W1, b1, W2, b2, outp);
}